// Round 2
// baseline (352.818 us; speedup 1.0000x reference)
//
#include <hip/hip_runtime.h>

#define N_NODES 50000
#define N_EDGES 600000
#define DIM     128
#define RR      4
#define LL      2
#define GG      512
#define CC      8
#define NCB     196                       // coarse buckets (nodes >> 8)
#define EC      (N_EDGES / 4)             // 150000
#define FB      ((EC + 255) / 256)        // 586 hist blocks (256-thr kernels)
#define FB1     ((EC + 1023) / 1024)      // 147 sortA blocks (1024-thr kernel)
#define TB      ((N_NODES + 255) / 256)   // 196 tfill blocks
#define NBH     ((N_NODES + 63) / 64)     // 782 MFMA tile blocks
#define CB      (1026 + 3125)             // 4151 canon blocks

typedef short bf16x8 __attribute__((ext_vector_type(8)));
typedef float f32x4  __attribute__((ext_vector_type(4)));

// ---------- bf16 <-> f32 helpers ----------
__device__ __forceinline__ float bf16_to_f(unsigned short u) {
    return __uint_as_float(((unsigned int)u) << 16);
}
__device__ __forceinline__ unsigned short f_to_bf16(float f) {
    unsigned int u = __float_as_uint(f);
    u += 0x7FFFu + ((u >> 16) & 1u);   // RNE
    return (unsigned short)(u >> 16);
}
__device__ __forceinline__ float loadf(const void* p, long i, int isbf) {
    if (isbf) return bf16_to_f(((const unsigned short*)p)[i]);
    return ((const float*)p)[i];
}
__device__ __forceinline__ void storef(void* p, long i, float v, int isbf) {
    if (isbf) ((unsigned short*)p)[i] = f_to_bf16(v);
    else      ((float*)p)[i] = v;
}

// ---------- init: zero chist(196)+tb(16), dtype-detect (block 0); zero emb_acc (blocks 1..64) ----------
__global__ void cg_init(const unsigned int* __restrict__ xw, int* __restrict__ flag,
                        int* __restrict__ chist_tb, float4* __restrict__ emb0) {
    __shared__ int cnt;
    int b = blockIdx.x;
    int tid = threadIdx.x;
    if (b == 0) {
        if (tid < NCB + 16) chist_tb[tid] = 0;
        if (tid == 0) cnt = 0;
        __syncthreads();
        unsigned int w = xw[tid];
        unsigned int e = (w >> 7) & 0xFFu;
        atomicAdd(&cnt, (e >= 110u && e <= 133u) ? 1 : 0);
        __syncthreads();
        if (tid == 0) *flag = (cnt >= 128) ? 1 : 0;
    } else {
        // 64 blocks x 256 threads x 16B = 262144 B = GG*DIM*4
        emb0[(b - 1) * 256 + tid] = make_float4(0.f, 0.f, 0.f, 0.f);
    }
}

// ---------- fused: coarse-bucket + node-type histograms [0,FB) + canonicalization ----------
__global__ void cg_hist_canon(const int* __restrict__ edge_index, const int* __restrict__ node_type,
                              int* __restrict__ chist, int* __restrict__ tb,
                              const void* __restrict__ x,
                              const void* __restrict__ W_het, const void* __restrict__ b_het,
                              const void* __restrict__ conv_W, const void* __restrict__ fuse_W,
                              const void* __restrict__ conv_b, const void* __restrict__ fuse_b,
                              const int* __restrict__ flagp,
                              unsigned short* __restrict__ xb, unsigned short* __restrict__ Wt,
                              float* __restrict__ bhf,
                              unsigned short* __restrict__ M2t, float* __restrict__ cvec) {
    __shared__ float s[256];
    int bk = blockIdx.x;
    int tid = threadIdx.x;
    if (bk < FB) {
        __shared__ int lh[NCB];
        __shared__ int loc[4];
        for (int i = tid; i < NCB; i += 256) lh[i] = 0;
        if (tid < 4) loc[tid] = 0;
        __syncthreads();
        int t = bk * 256 + tid;
        if (t < EC) {
#pragma unroll
            for (int k = 0; k < 4; k++) {
                int d = edge_index[N_EDGES + t + k * EC];
                atomicAdd(&lh[d >> 8], 1);
            }
        }
        if (t < N_NODES) atomicAdd(&loc[node_type[t]], 1);
        __syncthreads();
        for (int i = tid; i < NCB; i += 256)
            if (lh[i]) atomicAdd(&chist[i], lh[i]);
        if (tid < 4 && loc[tid]) atomicAdd(&tb[tid], loc[tid]);
        return;
    }
    int b = bk - FB;
    int isbf = *flagp;
    if (b < 512) {                      // M2t: 2 d-rows per block
        int lr = b >> 6;
        int d  = (b & 63) * 2 + (tid >> 7);
        int r  = lr & 3;
        int o  = tid & 127;
        float acc = 0.0f;
        for (int k = 0; k < DIM; k++) {
            acc += loadf(conv_W, (long)(lr * DIM + d) * DIM + k, isbf)
                 * loadf(fuse_W, (long)(r * DIM + k) * DIM + o, isbf);
        }
        M2t[((long)lr * DIM + o) * DIM + d] = f_to_bf16(acc);
    } else if (b < 768) {               // cvec
        int bc = b - 512;
        int l  = bc >> 7;
        int o  = bc & 127;
        float part = 0.0f;
        for (int rk = tid; rk < RR * DIM; rk += 256) {
            part += loadf(conv_b, (long)l * RR * DIM + rk, isbf)
                  * loadf(fuse_W, (long)rk * DIM + o, isbf);
        }
        s[tid] = part;
        __syncthreads();
        for (int off = 128; off > 0; off >>= 1) {
            if (tid < off) s[tid] += s[tid + off];
            __syncthreads();
        }
        if (tid == 0) cvec[bc] = s[0] + loadf(fuse_b, o, isbf);
    } else if (b < 1024) {              // Wt[t][o][d]; 2 (t,o) per block
        int pair = (b - 768) * 2 + (tid >> 7);
        int t = pair >> 7;
        int o = pair & 127;
        int d = tid & 127;
        float v = loadf(W_het, ((long)t * DIM + d) * DIM + o, isbf);
        Wt[((long)t * DIM + o) * DIM + d] = f_to_bf16(v);
    } else if (b < 1026) {              // bhf
        int idx = (b - 1024) * 256 + tid;
        if (idx < 4 * DIM) bhf[idx] = loadf(b_het, idx, isbf);
    } else {                            // xb: 8 elems/thread
        long i = ((long)(b - 1026) * 256 + tid) * 8;
        if (i >= (long)N_NODES * DIM) return;
        if (isbf) {
            *(uint4*)(xb + i) = *(const uint4*)((const unsigned short*)x + i);
        } else {
            const float* xf = (const float*)x + i;
            float4 f0 = *(const float4*)xf;
            float4 f1 = *(const float4*)(xf + 4);
            uint4 o;
            o.x = (unsigned int)f_to_bf16(f0.x) | ((unsigned int)f_to_bf16(f0.y) << 16);
            o.y = (unsigned int)f_to_bf16(f0.z) | ((unsigned int)f_to_bf16(f0.w) << 16);
            o.z = (unsigned int)f_to_bf16(f1.x) | ((unsigned int)f_to_bf16(f1.y) << 16);
            o.w = (unsigned int)f_to_bf16(f1.z) | ((unsigned int)f_to_bf16(f1.w) << 16);
            *(uint4*)(xb + i) = o;
        }
    }
}

// ---------- single-block: scan coarse hist -> blockoff/ccursor; scan tb ----------
__global__ void cg_scan196(const int* __restrict__ chist, int* __restrict__ blockoff,
                           int* __restrict__ ccursor, int* __restrict__ tb) {
    __shared__ int s[256];
    int tid = threadIdx.x;
    int v = (tid < NCB) ? chist[tid] : 0;
    s[tid] = v;
    __syncthreads();
    for (int off = 1; off < 256; off <<= 1) {
        int a = (tid >= off) ? s[tid - off] : 0;
        __syncthreads();
        s[tid] += a;
        __syncthreads();
    }
    if (tid < NCB) {
        int e = s[tid] - v;            // exclusive bucket start
        blockoff[tid] = e;
        ccursor[tid]  = e;
    }
    if (tid == 0) {
        int run = 0;
        for (int t = 0; t < 4; t++) {
            tb[8 + t] = run;
            tb[4 + t] = run;
            run += tb[t];
        }
        tb[12] = run;
    }
}

// ---------- node-type list fill (block-aggregated) ----------
__global__ void cg_tfill(const int* __restrict__ node_type, int* __restrict__ tb,
                         int* __restrict__ tlist) {
    __shared__ int lcur[4];
    __shared__ int lbase[4];
    int tid = threadIdx.x;
    if (tid < 4) lcur[tid] = 0;
    __syncthreads();
    int n = blockIdx.x * 256 + tid;
    int slot = -1, t = 0;
    if (n < N_NODES) {
        t = node_type[n];
        slot = atomicAdd(&lcur[t], 1);
    }
    __syncthreads();
    if (tid < 4) lbase[tid] = atomicAdd(&tb[4 + tid], lcur[tid]);
    __syncthreads();
    if (n < N_NODES) tlist[lbase[t] + slot] = n;
}

// ================= MFMA tiles (1024-thr, 16-wave; B read direct from L2) =================
#define APAD 136

// 16-wave fused 4-relation projection off an LDS A-tile (h rows already in a_lds).
// wave wv: rb = wv&3 (16 A-rows), cpair = wv>>2 (2 output col-blocks). B direct from global.
__device__ __forceinline__ void pgemm4r_16w(const unsigned short* __restrict__ M2base,
                                            unsigned short* __restrict__ P,
                                            const int* __restrict__ sids,   // LDS ids or nullptr
                                            int n0, int nlim, int tx,
                                            unsigned short a_lds[64][APAD]) {
    int wv = tx >> 6, lane = tx & 63;
    int m16 = lane & 15, quad = lane >> 4;
    int rb = wv & 3, cpair = wv >> 2;
    bf16x8 af[4];
#pragma unroll
    for (int ks = 0; ks < 4; ks++)
        af[ks] = *(const bf16x8*)(const void*)&a_lds[rb * 16 + m16][ks * 32 + quad * 8];
    for (int r = 0; r < 4; r++) {
        const unsigned short* B = M2base + (long)r * DIM * DIM;
        f32x4 acc[2];
        acc[0] = (f32x4){0.f, 0.f, 0.f, 0.f};
        acc[1] = (f32x4){0.f, 0.f, 0.f, 0.f};
#pragma unroll
        for (int ks = 0; ks < 4; ks++) {
            int koff = ks * 32 + quad * 8;
#pragma unroll
            for (int cc = 0; cc < 2; cc++) {
                bf16x8 bfr = *(const bf16x8*)(const void*)(B + (long)((cpair * 2 + cc) * 16 + m16) * DIM + koff);
                acc[cc] = __builtin_amdgcn_mfma_f32_16x16x32_bf16(af[ks], bfr, acc[cc], 0, 0, 0);
            }
        }
        __syncthreads();   // r=0: af preloads done everywhere; r>0: prior store reads done
#pragma unroll
        for (int cc = 0; cc < 2; cc++) {
            int col = (cpair * 2 + cc) * 16 + m16;
#pragma unroll
            for (int i = 0; i < 4; i++)
                a_lds[rb * 16 + quad * 4 + i][col] = f_to_bf16(acc[cc][i]);
        }
        __syncthreads();
        {
            int row = tx >> 4, seg = (tx & 15) * 8;
            bool ok; int n;
            if (sids) { ok = (row < nlim); n = ok ? sids[row] : 0; }
            else      { n = n0 + row; ok = (n < nlim); }
            if (ok)
                *(uint4*)(P + (long)n * (RR * DIM) + r * DIM + seg) = *(const uint4*)&a_lds[row][seg];
        }
    }
}

// ---------- fused: sort phase A [0,FB1) + hetero MFMA + pgemm l=0 [FB1, FB1+4*NBH) ----------
// h(0) never materialized: hetero output goes LDS -> pgemm A-frags -> P0 (tlist-scattered rows).
__global__ __launch_bounds__(1024, 8)
void cg_sortA_hetpg0(const int* __restrict__ edge_index, const int* __restrict__ edge_type,
                     int* __restrict__ ccursor, int2* __restrict__ tmp2,
                     const unsigned short* __restrict__ xb,
                     const unsigned short* __restrict__ Wt,
                     const float* __restrict__ bhf,
                     const int* __restrict__ tlist, const int* __restrict__ tb,
                     const unsigned short* __restrict__ M2t,
                     unsigned short* __restrict__ P0) {
    int bk = blockIdx.x;
    int tx = threadIdx.x;
    if (bk < FB1) {
        __shared__ int lhist[NCB];
        __shared__ int lbase[NCB];
        for (int i = tx; i < NCB; i += 1024) lhist[i] = 0;
        __syncthreads();
        int t = bk * 1024 + tx;
        int d[4], cb[4], ls[4], pl[4];
        bool act = (t < EC);
        if (act) {
#pragma unroll
            for (int k = 0; k < 4; k++) {
                int e = t + k * EC;
                d[k]  = edge_index[N_EDGES + e];
                pl[k] = (edge_index[e] << 2) | edge_type[e];
                cb[k] = d[k] >> 8;
                ls[k] = atomicAdd(&lhist[cb[k]], 1);
            }
        }
        __syncthreads();
        for (int i = tx; i < NCB; i += 1024)
            lbase[i] = lhist[i] ? atomicAdd(&ccursor[i], lhist[i]) : 0;
        __syncthreads();
        if (act) {
#pragma unroll
            for (int k = 0; k < 4; k++) {
                int pos = lbase[cb[k]] + ls[k];
                tmp2[pos] = make_int2(pl[k], d[k]);
            }
        }
        return;
    }
    int bb = bk - FB1;
    int t    = bb / NBH;
    int nblk = bb - t * NBH;
    int rows_base = tb[8 + t] + nblk * 64;
    int rend = tb[8 + t + 1];
    if (rows_base >= rend) return;
    int nvalid = rend - rows_base;
    if (nvalid > 64) nvalid = 64;
    __shared__ unsigned short a_lds[64][APAD];
    __shared__ int sids[64];
    if (tx < 64) sids[tx] = (tx < nvalid) ? tlist[rows_base + tx] : 0;
    __syncthreads();
    int wv = tx >> 6, lane = tx & 63;
    int m16 = lane & 15, quad = lane >> 4;
    int rb = wv & 3, cpair = wv >> 2;
    // A-frags direct from xb (tlist-gathered 16B loads)
    int an = sids[rb * 16 + m16];
    bf16x8 af[4];
#pragma unroll
    for (int ks = 0; ks < 4; ks++)
        af[ks] = *(const bf16x8*)(const void*)(xb + (long)an * DIM + ks * 32 + quad * 8);
    const unsigned short* Bw = Wt + (long)t * DIM * DIM;
    f32x4 acc[2];
    acc[0] = (f32x4){0.f, 0.f, 0.f, 0.f};
    acc[1] = (f32x4){0.f, 0.f, 0.f, 0.f};
#pragma unroll
    for (int ks = 0; ks < 4; ks++) {
        int koff = ks * 32 + quad * 8;
#pragma unroll
        for (int cc = 0; cc < 2; cc++) {
            bf16x8 bfr = *(const bf16x8*)(const void*)(Bw + (long)((cpair * 2 + cc) * 16 + m16) * DIM + koff);
            acc[cc] = __builtin_amdgcn_mfma_f32_16x16x32_bf16(af[ks], bfr, acc[cc], 0, 0, 0);
        }
    }
    // bias epilogue -> h(0) tile into a_lds (bf16, same rounding as before)
#pragma unroll
    for (int cc = 0; cc < 2; cc++) {
        int col = (cpair * 2 + cc) * 16 + m16;
        float bias = bhf[t * DIM + col];
#pragma unroll
        for (int i = 0; i < 4; i++)
            a_lds[rb * 16 + quad * 4 + i][col] = f_to_bf16(acc[cc][i] + bias);
    }
    __syncthreads();
    pgemm4r_16w(M2t, P0, sids, 0, nvalid, tx, a_lds);   // l = 0
}

// ---------- sort phase B (standalone): local count+scan -> rowptr + place ----------
__global__ void cg_sortB(const int2* __restrict__ tmp2, const int* __restrict__ blockoff,
                         int* __restrict__ rowptr, int* __restrict__ eidx) {
    __shared__ int lcnt[256];
    __shared__ int lscan[256];
    __shared__ int lcur[256];
    int bk = blockIdx.x;
    int tx = threadIdx.x;
    lcnt[tx] = 0;
    int base = blockoff[bk];
    int endp = (bk + 1 < NCB) ? blockoff[bk + 1] : N_EDGES;
    int cnt = endp - base;
    __syncthreads();
    for (int i = tx; i < cnt; i += 256)
        atomicAdd(&lcnt[tmp2[base + i].y & 255], 1);
    __syncthreads();
    int v = lcnt[tx];
    lscan[tx] = v;
    __syncthreads();
    for (int off = 1; off < 256; off <<= 1) {
        int a = (tx >= off) ? lscan[tx - off] : 0;
        __syncthreads();
        lscan[tx] += a;
        __syncthreads();
    }
    int start = base + lscan[tx] - v;    // exclusive
    lcur[tx] = start;
    int n = bk * 256 + tx;
    if (n < N_NODES) rowptr[n] = start;
    __syncthreads();
    for (int i = tx; i < cnt; i += 256) {
        int2 e = tmp2[base + i];
        int pos = atomicAdd(&lcur[e.y & 255], 1);
        eidx[pos] = e.x;
    }
}

// ---------- fused: gather l=0 (P0 -> h-tile in LDS) + pgemm l=1 (-> P1) ----------
// 1024 thr / 16 waves; each wave gathers 4 dst rows then joins the 16-wave pgemm.
__global__ __launch_bounds__(1024, 8)
void cg_gather_pgemm1(const unsigned short* __restrict__ P0, const int* __restrict__ rowptr,
                      const int* __restrict__ eidx, const float* __restrict__ cv,
                      const unsigned short* __restrict__ M2t,
                      unsigned short* __restrict__ P1) {
    __shared__ unsigned short a_lds[64][APAD];
    int tx = threadIdx.x;
    int n0 = blockIdx.x * 64;
    int wv = tx >> 6, lane = tx & 63;
    int eg = lane >> 4, ol = lane & 15;
    for (int tt = 0; tt < 4; tt++) {
        int row = wv * 4 + tt;
        int wid = n0 + row;
        float a[8] = {0.f, 0.f, 0.f, 0.f, 0.f, 0.f, 0.f, 0.f};
        if (wid < N_NODES) {
            int start = rowptr[wid];
            int end   = (wid + 1 < N_NODES) ? rowptr[wid + 1] : N_EDGES;
            int j = start + eg;
            for (; j + 4 < end; j += 8) {
                int v0 = eidx[j];
                int v1 = eidx[j + 4];
                const uint4 w0 = *(const uint4*)(P0 + (long)(v0 >> 2) * (RR * DIM) + (v0 & 3) * DIM + ol * 8);
                const uint4 w1 = *(const uint4*)(P0 + (long)(v1 >> 2) * (RR * DIM) + (v1 & 3) * DIM + ol * 8);
                a[0] += bf16_to_f((unsigned short)(w0.x & 0xFFFFu)) + bf16_to_f((unsigned short)(w1.x & 0xFFFFu));
                a[1] += bf16_to_f((unsigned short)(w0.x >> 16))     + bf16_to_f((unsigned short)(w1.x >> 16));
                a[2] += bf16_to_f((unsigned short)(w0.y & 0xFFFFu)) + bf16_to_f((unsigned short)(w1.y & 0xFFFFu));
                a[3] += bf16_to_f((unsigned short)(w0.y >> 16))     + bf16_to_f((unsigned short)(w1.y >> 16));
                a[4] += bf16_to_f((unsigned short)(w0.z & 0xFFFFu)) + bf16_to_f((unsigned short)(w1.z & 0xFFFFu));
                a[5] += bf16_to_f((unsigned short)(w0.z >> 16))     + bf16_to_f((unsigned short)(w1.z >> 16));
                a[6] += bf16_to_f((unsigned short)(w0.w & 0xFFFFu)) + bf16_to_f((unsigned short)(w1.w & 0xFFFFu));
                a[7] += bf16_to_f((unsigned short)(w0.w >> 16))     + bf16_to_f((unsigned short)(w1.w >> 16));
            }
            if (j < end) {
                int v = eidx[j];
                const uint4 w = *(const uint4*)(P0 + (long)(v >> 2) * (RR * DIM) + (v & 3) * DIM + ol * 8);
                a[0] += bf16_to_f((unsigned short)(w.x & 0xFFFFu));
                a[1] += bf16_to_f((unsigned short)(w.x >> 16));
                a[2] += bf16_to_f((unsigned short)(w.y & 0xFFFFu));
                a[3] += bf16_to_f((unsigned short)(w.y >> 16));
                a[4] += bf16_to_f((unsigned short)(w.z & 0xFFFFu));
                a[5] += bf16_to_f((unsigned short)(w.z >> 16));
                a[6] += bf16_to_f((unsigned short)(w.w & 0xFFFFu));
                a[7] += bf16_to_f((unsigned short)(w.w >> 16));
            }
        }
#pragma unroll
        for (int i = 0; i < 8; i++) {
            a[i] += __shfl_xor(a[i], 16);
            a[i] += __shfl_xor(a[i], 32);
        }
        if (eg == 0) {
            int o0 = ol * 8;
            float v[8];
#pragma unroll
            for (int i = 0; i < 8; i++) {
                float s = a[i] + cv[o0 + i];
                v[i] = s > 0.0f ? s : 0.0f;
            }
            uint4 o4;
            o4.x = (unsigned int)f_to_bf16(v[0]) | ((unsigned int)f_to_bf16(v[1]) << 16);
            o4.y = (unsigned int)f_to_bf16(v[2]) | ((unsigned int)f_to_bf16(v[3]) << 16);
            o4.z = (unsigned int)f_to_bf16(v[4]) | ((unsigned int)f_to_bf16(v[5]) << 16);
            o4.w = (unsigned int)f_to_bf16(v[6]) | ((unsigned int)f_to_bf16(v[7]) << 16);
            *(uint4*)&a_lds[row][o0] = o4;
        }
    }
    __syncthreads();
    pgemm4r_16w(M2t + (long)RR * DIM * DIM, P1, nullptr, n0, N_NODES, tx, a_lds);   // l = 1
}

// ---------- gather (layer 1) fused with mean-pool accumulation ----------
__global__ void cg_gather_pool(const unsigned short* __restrict__ P, const int* __restrict__ rowptr,
                               const int* __restrict__ eidx, const float* __restrict__ cv,
                               const int* __restrict__ batch, float* __restrict__ emb_acc) {
    __shared__ float sm[4][DIM];
    __shared__ int sg[4];
    int wid  = (blockIdx.x * 256 + threadIdx.x) >> 6;
    int lane = threadIdx.x & 63;
    int tid  = threadIdx.x;
    int wv   = tid >> 6;
    int eg = lane >> 4;
    int ol = lane & 15;
    int start = rowptr[wid];
    int end   = (wid + 1 < N_NODES) ? rowptr[wid + 1] : N_EDGES;
    float a[8] = {0.f, 0.f, 0.f, 0.f, 0.f, 0.f, 0.f, 0.f};
    int j = start + eg;
    for (; j + 4 < end; j += 8) {
        int v0 = eidx[j];
        int v1 = eidx[j + 4];
        const uint4 w0 = *(const uint4*)(P + (long)(v0 >> 2) * (RR * DIM) + (v0 & 3) * DIM + ol * 8);
        const uint4 w1 = *(const uint4*)(P + (long)(v1 >> 2) * (RR * DIM) + (v1 & 3) * DIM + ol * 8);
        a[0] += bf16_to_f((unsigned short)(w0.x & 0xFFFFu)) + bf16_to_f((unsigned short)(w1.x & 0xFFFFu));
        a[1] += bf16_to_f((unsigned short)(w0.x >> 16))     + bf16_to_f((unsigned short)(w1.x >> 16));
        a[2] += bf16_to_f((unsigned short)(w0.y & 0xFFFFu)) + bf16_to_f((unsigned short)(w1.y & 0xFFFFu));
        a[3] += bf16_to_f((unsigned short)(w0.y >> 16))     + bf16_to_f((unsigned short)(w1.y >> 16));
        a[4] += bf16_to_f((unsigned short)(w0.z & 0xFFFFu)) + bf16_to_f((unsigned short)(w1.z & 0xFFFFu));
        a[5] += bf16_to_f((unsigned short)(w0.z >> 16))     + bf16_to_f((unsigned short)(w1.z >> 16));
        a[6] += bf16_to_f((unsigned short)(w0.w & 0xFFFFu)) + bf16_to_f((unsigned short)(w1.w & 0xFFFFu));
        a[7] += bf16_to_f((unsigned short)(w0.w >> 16))     + bf16_to_f((unsigned short)(w1.w >> 16));
    }
    if (j < end) {
        int v = eidx[j];
        const uint4 w = *(const uint4*)(P + (long)(v >> 2) * (RR * DIM) + (v & 3) * DIM + ol * 8);
        a[0] += bf16_to_f((unsigned short)(w.x & 0xFFFFu));
        a[1] += bf16_to_f((unsigned short)(w.x >> 16));
        a[2] += bf16_to_f((unsigned short)(w.y & 0xFFFFu));
        a[3] += bf16_to_f((unsigned short)(w.y >> 16));
        a[4] += bf16_to_f((unsigned short)(w.z & 0xFFFFu));
        a[5] += bf16_to_f((unsigned short)(w.z >> 16));
        a[6] += bf16_to_f((unsigned short)(w.w & 0xFFFFu));
        a[7] += bf16_to_f((unsigned short)(w.w >> 16));
    }
#pragma unroll
    for (int i = 0; i < 8; i++) {
        a[i] += __shfl_xor(a[i], 16);
        a[i] += __shfl_xor(a[i], 32);
    }
    if (lane == 0) sg[wv] = batch[wid];
    if (eg == 0) {
        int o0 = ol * 8;
#pragma unroll
        for (int i = 0; i < 8; i++) {
            float s = a[i] + cv[o0 + i];
            sm[wv][o0 + i] = s > 0.0f ? s : 0.0f;   // relu'd h, f32 (never materialized)
        }
    }
    __syncthreads();
    if (tid < DIM) {
        float s = sm[0][tid];
        int cg = sg[0];
#pragma unroll
        for (int w = 1; w < 4; w++) {
            if (sg[w] == cg) {
                s += sm[w][tid];
            } else {
                atomicAdd(&emb_acc[(long)cg * DIM + tid], s);
                cg = sg[w];
                s = sm[w][tid];
            }
        }
        atomicAdd(&emb_acc[(long)cg * DIM + tid], s);
    }
}

// ---------- finalize: divide pooled sums, write emb, compute logits ----------
__global__ void cg_finalize(const float* __restrict__ emb_acc, const int* __restrict__ batch,
                            const void* __restrict__ cls_W, const void* __restrict__ cls_b,
                            const int* __restrict__ flagp, void* __restrict__ out) {
    __shared__ float emb_s[DIM];
    int g   = blockIdx.x;
    int tid = threadIdx.x;
    int isbf = *flagp;
    int lo = 0, hi = N_NODES;
    while (lo < hi) { int mid = (lo + hi) >> 1; if (batch[mid] < g) lo = mid + 1; else hi = mid; }
    int start = lo;
    hi = N_NODES;
    while (lo < hi) { int mid = (lo + hi) >> 1; if (batch[mid] < g + 1) lo = mid + 1; else hi = mid; }
    int end = lo;
    int cnt = end - start;
    float inv = 1.0f / (float)(cnt > 1 ? cnt : 1);
    if (tid < DIM) {
        float e = emb_acc[(long)g * DIM + tid] * inv;
        emb_s[tid] = e;
        storef(out, (long)g * DIM + tid, e, isbf);
    }
    __syncthreads();
    if (tid < 128) {
        int c  = tid >> 4;
        int kk = tid & 15;
        float p = 0.0f;
#pragma unroll
        for (int k = kk * 8; k < kk * 8 + 8; k++)
            p += emb_s[k] * loadf(cls_W, (long)k * CC + c, isbf);
        p += __shfl_xor(p, 1);
        p += __shfl_xor(p, 2);
        p += __shfl_xor(p, 4);
        p += __shfl_xor(p, 8);
        if (kk == 0)
            storef(out, (long)GG * DIM + g * CC + c, p + loadf(cls_b, c, isbf), isbf);
    }
}

extern "C" void kernel_launch(void* const* d_in, const int* in_sizes, int n_in,
                              void* d_out, int out_size, void* d_ws, size_t ws_size,
                              hipStream_t stream) {
    const void* x      = d_in[0];
    const void* W_het  = d_in[1];
    const void* b_het  = d_in[2];
    const void* conv_W = d_in[3];
    const void* conv_b = d_in[4];
    const void* fuse_W = d_in[5];
    const void* fuse_b = d_in[6];
    const void* cls_W  = d_in[7];
    const void* cls_b  = d_in[8];
    const int* node_type  = (const int*)d_in[9];
    const int* edge_index = (const int*)d_in[10];
    const int* edge_type  = (const int*)d_in[11];
    const int* batch      = (const int*)d_in[12];

    // workspace layout (bytes)
    char* base = (char*)d_ws;
    unsigned short* P0       = (unsigned short*)(base + 0);           // 51,200,000
    unsigned short* P1       = (unsigned short*)(base + 51200000);    // 51,200,000
    unsigned short* xb       = (unsigned short*)(base + 102400000);   // 12,800,000
    unsigned short* Wt       = (unsigned short*)(base + 115200000);   //    131,072
    float*          bhf      = (float*)(base + 115331072);            //      2,048
    unsigned short* M2t      = (unsigned short*)(base + 115333120);   //    262,144
    float*          cvec     = (float*)(base + 115595264);            //      1,024
    int*            rowptr   = (int*)(base + 115596288);              //    200,000
    int*            chist    = (int*)(base + 115796320);              //  chist[196]+tb[16]
    int*            tb       = chist + NCB;
    int*            blockoff = (int*)(base + 115797184);              //        784
    int*            ccursor  = (int*)(base + 115797984);              //        784
    int*            eidx     = (int*)(base + 115798784);              //  2,400,000
    int*            tlist    = (int*)(base + 118198784);              //    200,000
    int*            flag     = (int*)(base + 118398784);              //          4
    int2*           tmp2     = (int2*)(base + 118398848);             //  4,800,000
    float*          emb_acc  = (float*)(base + 123198848);            //    262,144 (total ~123.5 MB)

    cg_init<<<65, 256, 0, stream>>>((const unsigned int*)x, flag, chist, (float4*)emb_acc);
    cg_hist_canon<<<FB + CB, 256, 0, stream>>>(edge_index, node_type, chist, tb,
                                               x, W_het, b_het, conv_W, fuse_W,
                                               conv_b, fuse_b, flag,
                                               xb, Wt, bhf, M2t, cvec);
    cg_scan196<<<1, 256, 0, stream>>>(chist, blockoff, ccursor, tb);
    cg_tfill<<<TB, 256, 0, stream>>>(node_type, tb, tlist);
    // sortA (coarse bin) alongside hetero+pgemm0 fused tiles (h(0) stays in LDS)
    cg_sortA_hetpg0<<<FB1 + 4 * NBH, 1024, 0, stream>>>(edge_index, edge_type, ccursor, tmp2,
                                                        xb, Wt, bhf, tlist, tb, M2t, P0);
    cg_sortB<<<NCB, 256, 0, stream>>>(tmp2, blockoff, rowptr, eidx);
    // gather l=0 fused with pgemm l=1 (h(1) stays in LDS)
    cg_gather_pgemm1<<<NBH, 1024, 0, stream>>>(P0, rowptr, eidx, cvec, M2t, P1);
    // gather l=1 fused with mean-pool accumulation
    cg_gather_pool<<<(N_NODES * 64 + 255) / 256, 256, 0, stream>>>(
        P1, rowptr, eidx, cvec + DIM, batch, emb_acc);
    cg_finalize<<<GG, 256, 0, stream>>>(emb_acc, batch, cls_W, cls_b, flag, d_out);
}